// Round 11
// baseline (931.241 us; speedup 1.0000x reference)
//
#include <hip/hip_runtime.h>
#include <hip/hip_bf16.h>
#include <math.h>

// Problem constants (fixed by reference setup_inputs)
constexpr int NROWS = 8192;   // B
constexpr int HDIM  = 256;    // H (= K of the GEMM)
constexpr int N2    = 16384;  // 2*B rows of Z
constexpr int TM    = 256;    // tile M = tile N; 16 waves of 64x64 out each
constexpr int BK    = 32;     // K chunk staged per round (8 chunks)
constexpr int NCHUNK = HDIM / BK;     // 8
constexpr int PIECE = TM * BK;        // 8192 elems = 16 KB per piece
constexpr int NTILE = N2 / TM;        // 64 tile-rows
constexpr int NBLK  = NTILE * (NTILE + 1) / 2;  // 2080 upper-tri tiles

// sqrt(2 * log2(e)): Z pre-scaled so Zs_i.Zs_j = 2*log2(e)*cos and
// exp2(acc) == exp(sim/tau), tau = 0.5
constexpr float PRESCALE = 1.69864357f;

typedef __attribute__((ext_vector_type(4))) float floatx4;
typedef __attribute__((ext_vector_type(8))) short shortx8; // 8 bf16 = 4 VGPRs

__device__ __forceinline__ void async_copy16(const void* gptr, void* lptr) {
    __builtin_amdgcn_global_load_lds(
        (const __attribute__((address_space(1))) unsigned int*)gptr,
        (__attribute__((address_space(3))) unsigned int*)lptr, 16, 0, 0);
}

// s_waitcnt immediates (gfx9: vm[3:0], exp[6:4], lgkm[11:8], vm-hi[15:14])
#define WAIT_VM0()   __builtin_amdgcn_s_waitcnt(0x0F70)  // vmcnt(0)
#define MEMFENCE()   __asm__ __volatile__("" ::: "memory")
#define RAW_BARRIER() do { MEMFENCE(); __builtin_amdgcn_s_barrier(); MEMFENCE(); } while (0)

// DPP row_shl add: VALU pipe, not DS (R9: -18us vs ds_bpermute shuffles).
#define DPP_ROW_SHL_ADD(v, CTRL) do {                                        \
    union { float f; int i; } _u, _r; _u.f = (v);                            \
    _r.i = __builtin_amdgcn_update_dpp(0, _u.i, (CTRL), 0xF, 0xF, true);     \
    (v) += _r.f; } while (0)

// ---------------------------------------------------------------------------
// Kernel 1: wave-per-row L2-normalize -> bf16 Z (pre-scaled); pos = cos(x,y).
// Also zeroes rowsum and out (stream-ordered before consumers).
// ---------------------------------------------------------------------------
__global__ __launch_bounds__(256) void normalize_kernel(
    const float* __restrict__ x, const float* __restrict__ y,
    __hip_bfloat16* __restrict__ Z, float* __restrict__ pos,
    float* __restrict__ rowsum, float* __restrict__ out)
{
    const int wave = threadIdx.x >> 6, lane = threadIdx.x & 63;
    const int row  = blockIdx.x * 4 + wave;           // grid 2048 -> 8192 rows

    const float4 xv = ((const float4*)x)[row * 64 + lane];
    const float4 yv = ((const float4*)y)[row * 64 + lane];

    float sx  = xv.x*xv.x + xv.y*xv.y + xv.z*xv.z + xv.w*xv.w;
    float sy  = yv.x*yv.x + yv.y*yv.y + yv.z*yv.z + yv.w*yv.w;
    float sxy = xv.x*yv.x + xv.y*yv.y + xv.z*yv.z + xv.w*yv.w;
    #pragma unroll
    for (int m = 1; m < 64; m <<= 1) {
        sx  += __shfl_xor(sx,  m);
        sy  += __shfl_xor(sy,  m);
        sxy += __shfl_xor(sxy, m);
    }
    const float rxn = rsqrtf(sx), ryn = rsqrtf(sy);
    const float rx = rxn * PRESCALE, ry = ryn * PRESCALE;

    union { ushort4 u; __hip_bfloat16 h[4]; } zx, zy;
    zx.h[0] = __float2bfloat16(xv.x * rx); zx.h[1] = __float2bfloat16(xv.y * rx);
    zx.h[2] = __float2bfloat16(xv.z * rx); zx.h[3] = __float2bfloat16(xv.w * rx);
    zy.h[0] = __float2bfloat16(yv.x * ry); zy.h[1] = __float2bfloat16(yv.y * ry);
    zy.h[2] = __float2bfloat16(yv.z * ry); zy.h[3] = __float2bfloat16(yv.w * ry);
    ((ushort4*)Z)[row * 64 + lane]             = zx.u;
    ((ushort4*)Z)[(row + NROWS) * 64 + lane]   = zy.u;

    if (lane == 0) {
        const float p = sxy * rxn * ryn;
        pos[row]         = p;
        pos[row + NROWS] = p;
    }
    const int gt = blockIdx.x * 256 + threadIdx.x;
    if (gt < N2) rowsum[gt] = 0.f;
    if (gt == 0) out[0] = 0.f;
}

// ---------------------------------------------------------------------------
// Kernel 2: upper-triangle tiled Z·Z^T, fused exp2 + row/col sums.
// R19: R16 chassis (bf16 16x16x32, 16 waves x 64x64, BK=32, staging XOR +
// frag sw swizzle verbatim, 0 conflicts) with TWO LDS buffers (66KB) and
// __launch_bounds__(1024,8) -> TWO INDEPENDENT blocks per CU (8 waves/SIMD).
// Rationale: the 12-variant plateau (24-30% MfmaUtil) survived tile size,
// phase structure, prefetch depth, bytes (fp8), chunk count, MFMA shape,
// and SAME-BLOCK occupancy (R16: 4 waves/SIMD, all barrier-locked
// together -> stall together). R14's 2-blocks/CU attempt silently failed:
// (512,2) bounds let regalloc use 244 regs -> 2-wave cap -> second block
// never resident. This config is the first with genuinely independent
// wave groups per SIMD: block A's barrier/gate/prologue/epilogue stalls
// are filled by block B's MFMA bursts (m114 co-scheduling). Regs: 64 acc
// + ~60 VGPR = 124 <= 256/wave budget at 8 waves/SIMD; LDS 2x66 <= 160KB;
// threads 2x1024 = 2048 = CU max. setprio dropped (m190: hurts lockstep
// GEMM; want fair arbitration between blocks).
// Schedule (R14's proven 2-buffer WAR-safe variant):
//   body s: WAIT_VM0 (chunk-s loads, issued last body, sole outstanding);
//           BARRIER (buf s&1 landed for all); if s+1<8 STAGE(s+1) -> buf
//           (s+1)&1 [= buf read in body s-1; all waves' body-(s-1)
//           ds_reads retired before this barrier: compiler lgkm gates
//           precede their MFMAs, DS retires in-order];
//           ds_read buf s&1; 16 MFMA.
// No device-scope fences (R5). No direct-from-global frags (R7).
// ---------------------------------------------------------------------------
__global__ __launch_bounds__(1024, 8) void simgemm_kernel(
    const __hip_bfloat16* __restrict__ Z, float* __restrict__ rowsum)
{
    // ---- XCD-local block -> (bi,bj) mapping (bijection onto upper tri) ----
    // 2080 = 8 XCDs x 260; per XCD: 36 diag-group tiles + 7 off-diag halves(4x8)
    const int b = blockIdx.x;
    const int k = b & 7;        // XCD under round-robin dispatch heuristic
    const int m = b >> 3;       // 0..259 local rank within XCD
    int bi, bj;
    if (m < 36) {
        // diagonal group k: 8x8 upper triangle, cum(t) = t*(17-t)/2
        int ti = (int)((17.0f - sqrtf(289.0f - 8.0f * (float)m)) * 0.5f);
        if (m < ti * (17 - ti) / 2) ti--;
        else if (m >= (ti + 1) * (16 - ti) / 2) ti++;
        const int tj = ti + (m - ti * (17 - ti) / 2);
        bi = k * 8 + ti;
        bj = k * 8 + tj;
    } else {
        const int m2 = m - 36;           // 0..223
        const int hh = m2 >> 5;          // 0..6  (which of my 7 halves)
        const int r  = m2 & 31;          // 0..31 within half (4x8 tiles)
        const int h  = hh * 8 + k;       // 0..55 global half index
        const int q  = h >> 1;           // 0..27 off-diag group pair
        const int sub = h & 1;
        // pair q -> (gi,gj), gi<gj<8, cum(gi) = gi*(15-gi)/2
        int gi = 0;
        #pragma unroll
        for (int t = 6; t > 0; --t)
            if (q >= t * (15 - t) / 2) { gi = t; break; }
        const int gj = gi + 1 + (q - gi * (15 - gi) / 2);
        bi = gi * 8 + sub * 4 + (r >> 3);
        bj = gj * 8 + (r & 7);
    }
    const bool diag = (bi == bj);

    // LDS: 2 buffers x (tA 16KB + tB 16KB) = 64KB, + rs/cs 2KB = 66KB
    __shared__ alignas(16) __hip_bfloat16 tiles[4 * PIECE];  // 64 KB
    __shared__ float rs[TM];
    __shared__ float cs[TM];
    __hip_bfloat16* tA = tiles;                  // + buf * 2*PIECE
    __hip_bfloat16* tB = tiles + PIECE;          // + buf * 2*PIECE

    const int tid  = threadIdx.x;
    const int wave = tid >> 6;            // 0..15
    const int lane = tid & 63;
    const int wm   = wave & 3;            // wave row band (0..3): rows wm*64..+64
    const int wn   = wave >> 2;           // wave col band (0..3): cols wn*64..+64
    const int g    = lane >> 4;           // quad  (0..3)
    const int m15  = lane & 15;

    if (tid < TM) { rs[tid] = 0.f; cs[tid] = 0.f; }

    // ---- staging addresses (verbatim R16) ----
    // wave w stages rows [w*16, w*16+16) of A and of B per chunk.
    // lane l -> row w*16+(l>>2), lds 16B-slot l&3, src slot (l&3)^((l>>3)&3)
    const int st_r0  = wave * 16 + (lane >> 2);
    const int st_c   = (lane & 3) ^ ((lane >> 3) & 3);     // source chunk
    const __hip_bfloat16* gA0 = Z + (size_t)(bi * TM + st_r0) * HDIM + st_c * 8;
    const __hip_bfloat16* gB0 = Z + (size_t)(bj * TM + st_r0) * HDIM + st_c * 8;
    // wave-uniform LDS bases (lane scatter is +l*16B)
    __hip_bfloat16* lA0 = tA + (wave * 16) * BK;
    __hip_bfloat16* lB0 = tB + (wave * 16) * BK;

    // ---- fragment read addresses (all f-offsets immediates) ----
    const int sw = g ^ ((m15 >> 1) & 3);
    const __hip_bfloat16* rA = tA + (wm * 64 + m15) * BK + sw * 8;
    const __hip_bfloat16* rB = tB + (wn * 64 + m15) * BK + sw * 8;

    floatx4 acc[4][4] = {};

    // chunk ck -> buffer ck&1
    #define STAGE(ck)  do {                                                  \
        const int _o = ((ck) & 1) * 2 * PIECE;                               \
        async_copy16(gA0 + (ck) * BK, lA0 + _o);                             \
        async_copy16(gB0 + (ck) * BK, lB0 + _o);                             \
    } while (0)

    STAGE(0);   // prologue (2 loads in flight entering body 0)

    #pragma unroll
    for (int s = 0; s < NCHUNK; ++s) {
        WAIT_VM0();      // chunk-s loads (sole outstanding) retired, per-wave
        RAW_BARRIER();   // collectivize: buf s&1 fully landed for all waves
        if (s + 1 < NCHUNK) STAGE(s + 1);   // AFTER barrier: WAR-safe (hdr)

        const int bo = (s & 1) * 2 * PIECE;
        shortx8 af[4], bfr[4];
        #pragma unroll
        for (int f = 0; f < 4; ++f) {
            af[f]  = *(const shortx8*)(rA + bo + f * 16 * BK);
            bfr[f] = *(const shortx8*)(rB + bo + f * 16 * BK);
        }
        #pragma unroll
        for (int fm = 0; fm < 4; ++fm)
            #pragma unroll
            for (int fn = 0; fn < 4; ++fn)
                acc[fm][fn] = __builtin_amdgcn_mfma_f32_16x16x32_bf16(
                    af[fm], bfr[fn], acc[fm][fn], 0, 0, 0);
    }
    #undef STAGE

    // ---- epilogue: e = exp2(acc) (== exp(sim/tau)), reduce rows & cols ----
    float rp[4][4] = {{0.f}};  // [fm][reg] partial row sums
    float cp[4]    = {0.f};    // [fn]      partial col sums

    if (!diag) {
        #pragma unroll
        for (int fm = 0; fm < 4; ++fm)
            #pragma unroll
            for (int fn = 0; fn < 4; ++fn) {
                const floatx4 a = acc[fm][fn];
                #pragma unroll
                for (int q = 0; q < 4; ++q) {
                    const float e = __builtin_amdgcn_exp2f(a[q]);
                    rp[fm][q] += e;
                    cp[fn]    += e;
                }
            }
    } else {
        #pragma unroll
        for (int fm = 0; fm < 4; ++fm)
            #pragma unroll
            for (int fn = 0; fn < 4; ++fn) {
                const floatx4 a = acc[fm][fn];
                const int cl = wn * 64 + fn * 16 + m15;
                #pragma unroll
                for (int q = 0; q < 4; ++q) {
                    const int rl = wm * 64 + fm * 16 + g * 4 + q;
                    float e = __builtin_amdgcn_exp2f(a[q]);
                    if (cl <= rl) e = 0.f;   // strictly-upper only
                    rp[fm][q] += e;
                    cp[fn]    += e;
                }
            }
    }

    // row sums: 16-lane DPP reduction (VALU pipe); total lands in m15==0
    #pragma unroll
    for (int fm = 0; fm < 4; ++fm)
        #pragma unroll
        for (int q = 0; q < 4; ++q) {
            float v = rp[fm][q];
            DPP_ROW_SHL_ADD(v, 0x101);   // row_shl:1
            DPP_ROW_SHL_ADD(v, 0x102);   // row_shl:2
            DPP_ROW_SHL_ADD(v, 0x104);   // row_shl:4
            DPP_ROW_SHL_ADD(v, 0x108);   // row_shl:8
            rp[fm][q] = v;
        }
    if (m15 == 0) {
        #pragma unroll
        for (int fm = 0; fm < 4; ++fm)
            #pragma unroll
            for (int q = 0; q < 4; ++q)
                atomicAdd(&rs[wm * 64 + fm * 16 + g * 4 + q], rp[fm][q]);
    }

    // col sums: reduce across quads (xor 16/32 crosses DPP rows -> keep shfl)
    #pragma unroll
    for (int mask = 16; mask < 64; mask <<= 1)
        #pragma unroll
        for (int fn = 0; fn < 4; ++fn)
            cp[fn] += __shfl_xor(cp[fn], mask);
    if (g == 0) {
        #pragma unroll
        for (int fn = 0; fn < 4; ++fn)
            atomicAdd(&cs[wn * 64 + fn * 16 + m15], cp[fn]);
    }

    __syncthreads();
    if (tid < TM) {
        atomicAdd(&rowsum[(size_t)bi * TM + tid], rs[tid]);
        atomicAdd(&rowsum[(size_t)bj * TM + tid], cs[tid]);
    }
}

// ---------------------------------------------------------------------------
// Kernel 3: loss = mean( log(rowsum_i) - 2*pos_i ), 16 blocks + atomic.
// out[0] zeroed by normalize_kernel (stream-ordered).
// ---------------------------------------------------------------------------
__global__ __launch_bounds__(1024) void finalize_kernel(
    const float* __restrict__ rowsum, const float* __restrict__ pos,
    float* __restrict__ out)
{
    const int i = threadIdx.x + blockIdx.x * 1024;
    float s = logf(rowsum[i]) - 2.0f * pos[i];
    #pragma unroll
    for (int off = 32; off; off >>= 1) s += __shfl_down(s, off);
    __shared__ float sh[16];
    const int lt = threadIdx.x;
    if ((lt & 63) == 0) sh[lt >> 6] = s;
    __syncthreads();
    if (lt == 0) {
        float tot = 0.f;
        #pragma unroll
        for (int w = 0; w < 16; ++w) tot += sh[w];
        atomicAdd(out, tot / (float)N2);
    }
}

// ---------------------------------------------------------------------------
extern "C" void kernel_launch(void* const* d_in, const int* in_sizes, int n_in,
                              void* d_out, int out_size, void* d_ws, size_t ws_size,
                              hipStream_t stream)
{
    const float* x = (const float*)d_in[0];
    const float* y = (const float*)d_in[1];

    // workspace: Z bf16 [16384*256] (8 MB) | rowsum f32 [16384] | pos f32 [16384]
    __hip_bfloat16* Z = (__hip_bfloat16*)d_ws;
    float* rowsum = (float*)((char*)d_ws + (size_t)N2 * HDIM * sizeof(__hip_bfloat16));
    float* pos    = rowsum + N2;

    normalize_kernel<<<NROWS / 4, 256, 0, stream>>>(x, y, Z, pos, rowsum, (float*)d_out);
    simgemm_kernel<<<NBLK, 1024, 0, stream>>>(Z, rowsum);
    finalize_kernel<<<N2 / 1024, 1024, 0, stream>>>(rowsum, pos, (float*)d_out);
}

// Round 13
// 180.336 us; speedup vs baseline: 5.1639x; 5.1639x over previous
//
#include <hip/hip_runtime.h>
#include <hip/hip_bf16.h>
#include <math.h>

// Problem constants (fixed by reference setup_inputs)
constexpr int NROWS = 8192;   // B
constexpr int HDIM  = 256;    // H (= K of the GEMM); also bytes/row in fp8
constexpr int N2    = 16384;  // 2*B rows of Z
constexpr int TM    = 256;    // tile M = tile N; 16 waves of 64x64 out each
constexpr int TILEB = TM * HDIM;      // 64 KB per fp8 tile (A or B)
constexpr int NTILE = N2 / TM;        // 64 tile-rows
constexpr int NBLK  = NTILE * (NTILE + 1) / 2;  // 2080 upper-tri tiles

// sqrt(2 * log2(e)): Z pre-scaled so Zs_i.Zs_j = 2*log2(e)*cos and
// exp2(acc) == exp(sim/tau), tau = 0.5
constexpr float PRESCALE = 1.69864357f;

typedef __attribute__((ext_vector_type(4))) float floatx4;

__device__ __forceinline__ void async_copy16(const void* gptr, void* lptr) {
    __builtin_amdgcn_global_load_lds(
        (const __attribute__((address_space(1))) unsigned int*)gptr,
        (__attribute__((address_space(3))) unsigned int*)lptr, 16, 0, 0);
}

// s_waitcnt immediates (gfx9: vm[3:0], exp[6:4], lgkm[11:8], vm-hi[15:14])
#define WAIT_VM0()   __builtin_amdgcn_s_waitcnt(0x0F70)  // vmcnt(0)
#define MEMFENCE()   __asm__ __volatile__("" ::: "memory")
#define RAW_BARRIER() do { MEMFENCE(); __builtin_amdgcn_s_barrier(); MEMFENCE(); } while (0)

// DPP row_shl add: VALU pipe, not DS (R9: -18us vs ds_bpermute shuffles).
#define DPP_ROW_SHL_ADD(v, CTRL) do {                                        \
    union { float f; int i; } _u, _r; _u.f = (v);                            \
    _r.i = __builtin_amdgcn_update_dpp(0, _u.i, (CTRL), 0xF, 0xF, true);     \
    (v) += _r.f; } while (0)

// Manual RNE float -> OCP e4m3fn (1-4-3, bias 7, subnormals m*2^-9).
// Inputs here are |v| <~ 1.7 so no overflow path needed beyond clamp.
// [R17-verified: absmax 0.0]
__device__ __forceinline__ unsigned int f32_to_e4m3(float f) {
    const float a = fabsf(f);
    const unsigned int s = f < 0.f ? 0x80u : 0u;
    if (a < 0.015625f) {                       // subnormal: m = rne(a*512)
        int mm = (int)rintf(a * 512.0f);       // 0..8
        if (mm == 8) return s | 0x08u;         // rounds up to 2^-6
        return s | (unsigned int)mm;
    }
    int e; const float fr = frexpf(a, &e);     // a = fr*2^e, fr in [0.5,1)
    int mm = (int)rintf(fr * 16.0f) - 8;       // 0..8
    int E  = e + 6;                            // biased exponent
    if (mm == 8) { mm = 0; E += 1; }
    if (E > 15) { E = 15; mm = 6; }            // clamp to 448 (never hit)
    return s | (unsigned int)((E << 3) | mm);
}

// ---------------------------------------------------------------------------
// Kernel 1: wave-per-row L2-normalize -> FP8 e4m3 Z (pre-scaled);
// pos = cos(x,y) in exact fp32. Also zeroes rowsum and out. [R17 verbatim]
// ---------------------------------------------------------------------------
__global__ __launch_bounds__(256) void normalize_kernel(
    const float* __restrict__ x, const float* __restrict__ y,
    unsigned char* __restrict__ Zb, float* __restrict__ pos,
    float* __restrict__ rowsum, float* __restrict__ out)
{
    const int wave = threadIdx.x >> 6, lane = threadIdx.x & 63;
    const int row  = blockIdx.x * 4 + wave;           // grid 2048 -> 8192 rows

    const float4 xv = ((const float4*)x)[row * 64 + lane];
    const float4 yv = ((const float4*)y)[row * 64 + lane];

    float sx  = xv.x*xv.x + xv.y*xv.y + xv.z*xv.z + xv.w*xv.w;
    float sy  = yv.x*yv.x + yv.y*yv.y + yv.z*yv.z + yv.w*yv.w;
    float sxy = xv.x*yv.x + xv.y*yv.y + xv.z*yv.z + xv.w*yv.w;
    #pragma unroll
    for (int m = 1; m < 64; m <<= 1) {
        sx  += __shfl_xor(sx,  m);
        sy  += __shfl_xor(sy,  m);
        sxy += __shfl_xor(sxy, m);
    }
    const float rxn = rsqrtf(sx), ryn = rsqrtf(sy);
    const float rx = rxn * PRESCALE, ry = ryn * PRESCALE;

    const unsigned int px =
        f32_to_e4m3(xv.x * rx)        | (f32_to_e4m3(xv.y * rx) << 8) |
        (f32_to_e4m3(xv.z * rx) << 16) | (f32_to_e4m3(xv.w * rx) << 24);
    const unsigned int py =
        f32_to_e4m3(yv.x * ry)        | (f32_to_e4m3(yv.y * ry) << 8) |
        (f32_to_e4m3(yv.z * ry) << 16) | (f32_to_e4m3(yv.w * ry) << 24);

    ((unsigned int*)Zb)[row * 64 + lane]             = px;  // 4 B/lane
    ((unsigned int*)Zb)[(row + NROWS) * 64 + lane]   = py;

    if (lane == 0) {
        const float p = sxy * rxn * ryn;   // exact fp32 numerator path
        pos[row]         = p;
        pos[row + NROWS] = p;
    }
    const int gt = blockIdx.x * 256 + threadIdx.x;
    if (gt < N2) rowsum[gt] = 0.f;
    if (gt == 0) out[0] = 0.f;
}

// ---------------------------------------------------------------------------
// Kernel 2: upper-triangle tiled Z·Z^T (FP8), fused exp2 + row/col sums.
// R20 (resubmitted after infra failure; audited: no deadlock — one vm0 +
// one unconditional barrier; no OOB; staging<->read layout identity
// re-verified algebraically; ~110 regs <= 128 at (1024,4)):
// SINGLE-SHOT WHOLE-K. fp8 makes a full 256x256 tile 64KB, so A and B
// both fit in LDS (128KB + 2KB <= 160KB). Stage EVERYTHING once (8
// global_load_lds per wave), ONE vmcnt(0), ONE barrier, then the K-loop is
// pure {ds_read_b64 + MFMA} with ZERO barriers/gates/re-staging — LDS is
// read-only after the barrier, so WAR/RAW vanish by construction. This
// deletes the per-chunk sync structure that the 13-variant ledger
// identified as the 24-30% MfmaUtil plateau (2-phase family ceiling,
// m233; R19's 2-blocks/CU attempt died on m69's 64-reg budget at 8
// waves/SIMD — spilled; this keeps the proven (1024,4) = 128-reg regime).
// Per-SIMD budget: MFMA 8.2k cyc, frag ds-traffic 4.1k cyc (2x headroom),
// prologue ~1.5k exposed once per block.
// Staging (R17 XOR scheme per 64B window): copy c of 4 covers rows
// w*16+c*4..+3; lane l -> row w*16+c*4+(l>>4), window (l&15)>>2, LDS slot
// l&3; source slot = (l&3) ^ xr, xr=(row>>1)&3=(2c+(l>>5))&3 -> alternates
// between (l>>5) [c even] and (2+(l>>5))&3 [c odd].
// Frag reads (R17 verbatim): kstep t: off = (t>>1)*64 +
// ((((t&1)*2+(g>>1))^xr)*16) + (g&1)*8, xr=(m15>>1)&3. A/B same formula ->
// any k-permutation cancels in the dot. ~4-way bank aliasing accepted.
// ---------------------------------------------------------------------------
__global__ __launch_bounds__(1024, 4) void simgemm_kernel(
    const unsigned char* __restrict__ Zb, float* __restrict__ rowsum)
{
    // ---- XCD-local block -> (bi,bj) mapping (bijection onto upper tri) ----
    const int b = blockIdx.x;
    const int k = b & 7;        // XCD under round-robin dispatch heuristic
    const int m = b >> 3;       // 0..259 local rank within XCD
    int bi, bj;
    if (m < 36) {
        int ti = (int)((17.0f - sqrtf(289.0f - 8.0f * (float)m)) * 0.5f);
        if (m < ti * (17 - ti) / 2) ti--;
        else if (m >= (ti + 1) * (16 - ti) / 2) ti++;
        const int tj = ti + (m - ti * (17 - ti) / 2);
        bi = k * 8 + ti;
        bj = k * 8 + tj;
    } else {
        const int m2 = m - 36;           // 0..223
        const int hh = m2 >> 5;          // 0..6
        const int r  = m2 & 31;          // 0..31
        const int h  = hh * 8 + k;       // 0..55
        const int q  = h >> 1;           // 0..27
        const int sub = h & 1;
        int gi = 0;
        #pragma unroll
        for (int t = 6; t > 0; --t)
            if (q >= t * (15 - t) / 2) { gi = t; break; }
        const int gj = gi + 1 + (q - gi * (15 - gi) / 2);
        bi = gi * 8 + sub * 4 + (r >> 3);
        bj = gj * 8 + (r & 7);
    }
    const bool diag = (bi == bj);

    // LDS: A tile 64KB | B tile 64KB | rs/cs 2KB = 130KB (1 block/CU)
    __shared__ alignas(16) unsigned char tiles[2 * TILEB];  // 128 KB
    __shared__ float rs[TM];
    __shared__ float cs[TM];

    const int tid  = threadIdx.x;
    const int wave = tid >> 6;            // 0..15
    const int lane = tid & 63;
    const int wm   = wave & 3;            // wave row band: rows wm*64..+64
    const int wn   = wave >> 2;           // wave col band: cols wn*64..+64
    const int g    = lane >> 4;           // quad (0..3)
    const int m15  = lane & 15;

    if (tid < TM) { rs[tid] = 0.f; cs[tid] = 0.f; }

    // ---- one-shot staging: wave w covers rows [w*16, w*16+16) of A and B.
    // 4 copies per matrix; copy c: rows w*16+c*4..+3 (1KB, lane l -> row
    // +(l>>4), within-row byte: window*64 + slot*16; source slot XOR'd).
    const int xr_e = (lane >> 5) & 3;             // xr for c even
    const int xr_o = (2 + (lane >> 5)) & 3;       // xr for c odd
    const int win  = ((lane & 15) >> 2) * 64;     // 64B window base
    const int soff_e = win + (((lane & 3) ^ xr_e) * 16);
    const int soff_o = win + (((lane & 3) ^ xr_o) * 16);
    const unsigned char* gA = Zb + (size_t)(bi * TM + wave * 16 + (lane >> 4)) * HDIM;
    const unsigned char* gB = Zb + (size_t)(bj * TM + wave * 16 + (lane >> 4)) * HDIM;
    unsigned char* lA = tiles + (wave * 16) * HDIM;          // +c*1024, +l*16
    unsigned char* lB = tiles + TILEB + (wave * 16) * HDIM;

    async_copy16(gA + 0 * 1024 + soff_e, lA + 0 * 1024);
    async_copy16(gA + 1 * 1024 + soff_o, lA + 1 * 1024);
    async_copy16(gA + 2 * 1024 + soff_e, lA + 2 * 1024);
    async_copy16(gA + 3 * 1024 + soff_o, lA + 3 * 1024);
    async_copy16(gB + 0 * 1024 + soff_e, lB + 0 * 1024);
    async_copy16(gB + 1 * 1024 + soff_o, lB + 1 * 1024);
    async_copy16(gB + 2 * 1024 + soff_e, lB + 2 * 1024);
    async_copy16(gB + 3 * 1024 + soff_o, lB + 3 * 1024);

    WAIT_VM0();        // own 8 copies retired
    RAW_BARRIER();     // all waves' copies landed; LDS read-only hereafter

    // ---- fragment read offsets (R17 verbatim) ----
    const int xr  = (m15 >> 1) & 3;
    const int slg = g >> 1;
    const int ha  = (g & 1) * 8;
    const int rowA = (wm * 64 + m15) * HDIM;
    const int rowB = (wn * 64 + m15) * HDIM;
    const unsigned char* bA = tiles;
    const unsigned char* bB = tiles + TILEB;

    floatx4 acc[4][4] = {};

    // ---- barrier-free K-loop: 8 ksteps x (8 ds_read_b64 + 16 MFMA) ----
    #pragma unroll
    for (int t = 0; t < 8; ++t) {
        const int off = (t >> 1) * 64 + (((((t & 1) << 1) + slg) ^ xr) * 16) + ha;
        long af[4], bfr[4];
        #pragma unroll
        for (int f = 0; f < 4; ++f) {
            af[f]  = *(const long*)(bA + rowA + f * 16 * HDIM + off);
            bfr[f] = *(const long*)(bB + rowB + f * 16 * HDIM + off);
        }
        #pragma unroll
        for (int fm = 0; fm < 4; ++fm)
            #pragma unroll
            for (int fn = 0; fn < 4; ++fn)
                acc[fm][fn] = __builtin_amdgcn_mfma_f32_16x16x32_fp8_fp8(
                    af[fm], bfr[fn], acc[fm][fn], 0, 0, 0);
    }

    // ---- epilogue: e = exp2(acc) (== exp(sim/tau)), reduce rows & cols ----
    float rp[4][4] = {{0.f}};  // [fm][reg] partial row sums
    float cp[4]    = {0.f};    // [fn]      partial col sums

    if (!diag) {
        #pragma unroll
        for (int fm = 0; fm < 4; ++fm)
            #pragma unroll
            for (int fn = 0; fn < 4; ++fn) {
                const floatx4 a = acc[fm][fn];
                #pragma unroll
                for (int q = 0; q < 4; ++q) {
                    const float e = __builtin_amdgcn_exp2f(a[q]);
                    rp[fm][q] += e;
                    cp[fn]    += e;
                }
            }
    } else {
        #pragma unroll
        for (int fm = 0; fm < 4; ++fm)
            #pragma unroll
            for (int fn = 0; fn < 4; ++fn) {
                const floatx4 a = acc[fm][fn];
                const int cl = wn * 64 + fn * 16 + m15;
                #pragma unroll
                for (int q = 0; q < 4; ++q) {
                    const int rl = wm * 64 + fm * 16 + g * 4 + q;
                    float e = __builtin_amdgcn_exp2f(a[q]);
                    if (cl <= rl) e = 0.f;   // strictly-upper only
                    rp[fm][q] += e;
                    cp[fn]    += e;
                }
            }
    }

    // row sums: 16-lane DPP reduction (VALU pipe); total lands in m15==0
    #pragma unroll
    for (int fm = 0; fm < 4; ++fm)
        #pragma unroll
        for (int q = 0; q < 4; ++q) {
            float v = rp[fm][q];
            DPP_ROW_SHL_ADD(v, 0x101);   // row_shl:1
            DPP_ROW_SHL_ADD(v, 0x102);   // row_shl:2
            DPP_ROW_SHL_ADD(v, 0x104);   // row_shl:4
            DPP_ROW_SHL_ADD(v, 0x108);   // row_shl:8
            rp[fm][q] = v;
        }
    if (m15 == 0) {
        #pragma unroll
        for (int fm = 0; fm < 4; ++fm)
            #pragma unroll
            for (int q = 0; q < 4; ++q)
                atomicAdd(&rs[wm * 64 + fm * 16 + g * 4 + q], rp[fm][q]);
    }

    // col sums: reduce across quads
    #pragma unroll
    for (int mask = 16; mask < 64; mask <<= 1)
        #pragma unroll
        for (int fn = 0; fn < 4; ++fn)
            cp[fn] += __shfl_xor(cp[fn], mask);
    if (g == 0) {
        #pragma unroll
        for (int fn = 0; fn < 4; ++fn)
            atomicAdd(&cs[wn * 64 + fn * 16 + m15], cp[fn]);
    }

    __syncthreads();
    if (tid < TM) {
        atomicAdd(&rowsum[(size_t)bi * TM + tid], rs[tid]);
        atomicAdd(&rowsum[(size_t)bj * TM + tid], cs[tid]);
    }
}

// ---------------------------------------------------------------------------
// Kernel 3: loss = mean( log(rowsum_i) - 2*pos_i ), 16 blocks + atomic.
// ---------------------------------------------------------------------------
__global__ __launch_bounds__(1024) void finalize_kernel(
    const float* __restrict__ rowsum, const float* __restrict__ pos,
    float* __restrict__ out)
{
    const int i = threadIdx.x + blockIdx.x * 1024;
    float s = logf(rowsum[i]) - 2.0f * pos[i];
    #pragma unroll
    for (int off = 32; off; off >>= 1) s += __shfl_down(s, off);
    __shared__ float sh[16];
    const int lt = threadIdx.x;
    if ((lt & 63) == 0) sh[lt >> 6] = s;
    __syncthreads();
    if (lt == 0) {
        float tot = 0.f;
        #pragma unroll
        for (int w = 0; w < 16; ++w) tot += sh[w];
        atomicAdd(out, tot / (float)N2);
    }
}

// ---------------------------------------------------------------------------
extern "C" void kernel_launch(void* const* d_in, const int* in_sizes, int n_in,
                              void* d_out, int out_size, void* d_ws, size_t ws_size,
                              hipStream_t stream)
{
    const float* x = (const float*)d_in[0];
    const float* y = (const float*)d_in[1];

    // workspace: Z fp8 [16384*256] (4 MB) | rowsum f32 [16384] | pos f32 [16384]
    unsigned char* Zb = (unsigned char*)d_ws;
    float* rowsum = (float*)((char*)d_ws + (size_t)N2 * HDIM);
    float* pos    = rowsum + N2;

    normalize_kernel<<<NROWS / 4, 256, 0, stream>>>(x, y, Zb, pos, rowsum, (float*)d_out);
    simgemm_kernel<<<NBLK, 1024, 0, stream>>>(Zb, rowsum);
    finalize_kernel<<<N2 / 1024, 1024, 0, stream>>>(rowsum, pos, (float*)d_out);
}

// Round 14
// 147.473 us; speedup vs baseline: 6.3146x; 1.2228x over previous
//
#include <hip/hip_runtime.h>
#include <hip/hip_bf16.h>
#include <math.h>

// Problem constants (fixed by reference setup_inputs)
constexpr int NROWS = 8192;   // B
constexpr int HDIM  = 256;    // H (= K of the GEMM); also bytes/row in fp8
constexpr int N2    = 16384;  // 2*B rows of Z
constexpr int TM    = 256;    // tile M = tile N; 16 waves of 64x64 out each
constexpr int TILEB = TM * HDIM;      // 64 KB per fp8 tile (A or B)
constexpr int NTILE = N2 / TM;        // 64 tile-rows
constexpr int NBLK  = NTILE * (NTILE + 1) / 2;  // 2080 upper-tri tiles

// sqrt(2 * log2(e)): Z pre-scaled so Zs_i.Zs_j = 2*log2(e)*cos and
// exp2(acc) == exp(sim/tau), tau = 0.5
constexpr float PRESCALE = 1.69864357f;

typedef __attribute__((ext_vector_type(4))) float floatx4;
typedef __attribute__((ext_vector_type(2))) long longx2;   // 16B LDS read

__device__ __forceinline__ void async_copy16(const void* gptr, void* lptr) {
    __builtin_amdgcn_global_load_lds(
        (const __attribute__((address_space(1))) unsigned int*)gptr,
        (__attribute__((address_space(3))) unsigned int*)lptr, 16, 0, 0);
}

// s_waitcnt immediates (gfx9: vm[3:0], exp[6:4], lgkm[11:8], vm-hi[15:14])
#define WAIT_VM0()   __builtin_amdgcn_s_waitcnt(0x0F70)  // vmcnt(0)
#define MEMFENCE()   __asm__ __volatile__("" ::: "memory")
#define RAW_BARRIER() do { MEMFENCE(); __builtin_amdgcn_s_barrier(); MEMFENCE(); } while (0)

// DPP row_shl add: VALU pipe, not DS (R9: -18us vs ds_bpermute shuffles).
#define DPP_ROW_SHL_ADD(v, CTRL) do {                                        \
    union { float f; int i; } _u, _r; _u.f = (v);                            \
    _r.i = __builtin_amdgcn_update_dpp(0, _u.i, (CTRL), 0xF, 0xF, true);     \
    (v) += _r.f; } while (0)

// Manual RNE float -> OCP e4m3fn (1-4-3, bias 7, subnormals m*2^-9).
// [R17-verified: absmax 0.0]
__device__ __forceinline__ unsigned int f32_to_e4m3(float f) {
    const float a = fabsf(f);
    const unsigned int s = f < 0.f ? 0x80u : 0u;
    if (a < 0.015625f) {                       // subnormal: m = rne(a*512)
        int mm = (int)rintf(a * 512.0f);       // 0..8
        if (mm == 8) return s | 0x08u;         // rounds up to 2^-6
        return s | (unsigned int)mm;
    }
    int e; const float fr = frexpf(a, &e);     // a = fr*2^e, fr in [0.5,1)
    int mm = (int)rintf(fr * 16.0f) - 8;       // 0..8
    int E  = e + 6;                            // biased exponent
    if (mm == 8) { mm = 0; E += 1; }
    if (E > 15) { E = 15; mm = 6; }            // clamp to 448 (never hit)
    return s | (unsigned int)((E << 3) | mm);
}

// ---------------------------------------------------------------------------
// Kernel 1: wave-per-row L2-normalize -> FP8 e4m3 Z, stored in sigma-permuted
// k-order (see R21 header in kernel 2). pos = cos(x,y) exact fp32.
// sigma: k = t*32 + g*8 + j (t=k>>5, g=(k>>3)&3, j=k&7) ->
//        pos = (t>>1)*64 + g*16 + (t&1)*8 + j.
// Lane holds k = lane*4..+3 (one uint): t=lane>>3, g=(lane>>1)&3,
// j = (lane&1)*4..+3 -> 4 consecutive sigma-positions, one uint store.
// k-permutation is harmless: A and B both read Z, dots are k-order
// invariant. Also zeroes rowsum and out.
// ---------------------------------------------------------------------------
__global__ __launch_bounds__(256) void normalize_kernel(
    const float* __restrict__ x, const float* __restrict__ y,
    unsigned char* __restrict__ Zb, float* __restrict__ pos,
    float* __restrict__ rowsum, float* __restrict__ out)
{
    const int wave = threadIdx.x >> 6, lane = threadIdx.x & 63;
    const int row  = blockIdx.x * 4 + wave;           // grid 2048 -> 8192 rows

    const float4 xv = ((const float4*)x)[row * 64 + lane];
    const float4 yv = ((const float4*)y)[row * 64 + lane];

    float sx  = xv.x*xv.x + xv.y*xv.y + xv.z*xv.z + xv.w*xv.w;
    float sy  = yv.x*yv.x + yv.y*yv.y + yv.z*yv.z + yv.w*yv.w;
    float sxy = xv.x*yv.x + xv.y*yv.y + xv.z*yv.z + xv.w*yv.w;
    #pragma unroll
    for (int m = 1; m < 64; m <<= 1) {
        sx  += __shfl_xor(sx,  m);
        sy  += __shfl_xor(sy,  m);
        sxy += __shfl_xor(sxy, m);
    }
    const float rxn = rsqrtf(sx), ryn = rsqrtf(sy);
    const float rx = rxn * PRESCALE, ry = ryn * PRESCALE;

    const unsigned int px =
        f32_to_e4m3(xv.x * rx)        | (f32_to_e4m3(xv.y * rx) << 8) |
        (f32_to_e4m3(xv.z * rx) << 16) | (f32_to_e4m3(xv.w * rx) << 24);
    const unsigned int py =
        f32_to_e4m3(yv.x * ry)        | (f32_to_e4m3(yv.y * ry) << 8) |
        (f32_to_e4m3(yv.z * ry) << 16) | (f32_to_e4m3(yv.w * ry) << 24);

    // sigma-permuted destination (4B aligned, same 256B segment per wave)
    const int t  = lane >> 3;
    const int gg = (lane >> 1) & 3;
    const int posb = (t >> 1) * 64 + gg * 16 + (t & 1) * 8 + (lane & 1) * 4;

    *(unsigned int*)(Zb + (size_t)row * HDIM + posb)           = px;
    *(unsigned int*)(Zb + (size_t)(row + NROWS) * HDIM + posb) = py;

    if (lane == 0) {
        const float p = sxy * rxn * ryn;   // exact fp32 numerator path
        pos[row]         = p;
        pos[row + NROWS] = p;
    }
    const int gt = blockIdx.x * 256 + threadIdx.x;
    if (gt < N2) rowsum[gt] = 0.f;
    if (gt == 0) out[0] = 0.f;
}

// ---------------------------------------------------------------------------
// Kernel 2: upper-triangle tiled Z·Z^T (FP8), fused exp2 + row/col sums.
// R21: R20's single-shot whole-K (one vm0 + one barrier, ZERO K-loop sync)
// with the bank-conflict bug fixed. R20's failure: 256B row stride ≡ 0 mod
// 32 banks -> 16 frag rows aliased, 25.6M conflicts (~12k cyc/block). Fix:
// Z stored in sigma k-order (see kernel 1) so a lane's operands for TWO
// ksteps are 16 contiguous bytes -> frag reads are ds_read_b128 at phys
// slot (u*4+g) ^ (m15&7). Bank audit: per b128, each 3-bit bank-group gets
// 8 lanes x 4 dwords evenly = 8 dwords/bank = structural minimum ->
// conflict-free; and frag-read instruction count halves (32 b128/wave).
// Per-SIMD budget: MFMA 8.2k cyc, frag LDS ~1.0k, stage ~0.3k.
// LDS layout: [row][16 phys slots of 16B]; phys = logical ^ (row&7) (low 3
// bits). Staging: wave w covers rows [w*16,+16) of A,B; copy c = 4 rows;
// lane l -> row w*16+4c+(l>>4), phys slot l&15 (dest linear = base+l*16),
// source slot = (l&15)^((4c+(l>>4))&7) -> se/so alternate by c parity.
// Frag reads (kstep-pair u, frag row f): b128 at
//   (band + f*16 + m15)*256 + (((u*4+g) ^ (m15&7)) * 16)
// low 8B = kstep 2u operand, high 8B = kstep 2u+1. A/B same formula.
// WAR/RAW: LDS read-only after the single barrier — vanish by construction.
// ---------------------------------------------------------------------------
__global__ __launch_bounds__(1024, 4) void simgemm_kernel(
    const unsigned char* __restrict__ Zb, float* __restrict__ rowsum)
{
    // ---- XCD-local block -> (bi,bj) mapping (bijection onto upper tri) ----
    const int b = blockIdx.x;
    const int k = b & 7;        // XCD under round-robin dispatch heuristic
    const int m = b >> 3;       // 0..259 local rank within XCD
    int bi, bj;
    if (m < 36) {
        int ti = (int)((17.0f - sqrtf(289.0f - 8.0f * (float)m)) * 0.5f);
        if (m < ti * (17 - ti) / 2) ti--;
        else if (m >= (ti + 1) * (16 - ti) / 2) ti++;
        const int tj = ti + (m - ti * (17 - ti) / 2);
        bi = k * 8 + ti;
        bj = k * 8 + tj;
    } else {
        const int m2 = m - 36;           // 0..223
        const int hh = m2 >> 5;          // 0..6
        const int r  = m2 & 31;          // 0..31
        const int h  = hh * 8 + k;       // 0..55
        const int q  = h >> 1;           // 0..27
        const int sub = h & 1;
        int gi = 0;
        #pragma unroll
        for (int t = 6; t > 0; --t)
            if (q >= t * (15 - t) / 2) { gi = t; break; }
        const int gj = gi + 1 + (q - gi * (15 - gi) / 2);
        bi = gi * 8 + sub * 4 + (r >> 3);
        bj = gj * 8 + (r & 7);
    }
    const bool diag = (bi == bj);

    // LDS: A tile 64KB | B tile 64KB | rs/cs 2KB = 130KB (1 block/CU)
    __shared__ alignas(16) unsigned char tiles[2 * TILEB];  // 128 KB
    __shared__ float rs[TM];
    __shared__ float cs[TM];

    const int tid  = threadIdx.x;
    const int wave = tid >> 6;            // 0..15
    const int lane = tid & 63;
    const int wm   = wave & 3;            // wave row band: rows wm*64..+64
    const int wn   = wave >> 2;           // wave col band: cols wn*64..+64
    const int g    = lane >> 4;           // quad (0..3)
    const int m15  = lane & 15;

    if (tid < TM) { rs[tid] = 0.f; cs[tid] = 0.f; }

    // ---- one-shot staging: wave w covers rows [w*16,+16) of A and B ----
    const int rl4 = lane >> 4;                    // row within 4-row copy
    const int se  = ((lane & 15) ^ rl4) * 16;           // c even source off
    const int so  = (((lane & 15) ^ rl4) ^ 4) * 16;     // c odd  source off
    const unsigned char* gA = Zb + (size_t)(bi * TM + wave * 16 + rl4) * HDIM;
    const unsigned char* gB = Zb + (size_t)(bj * TM + wave * 16 + rl4) * HDIM;
    unsigned char* lA = tiles + (wave * 16) * HDIM;          // + lane*16
    unsigned char* lB = tiles + TILEB + (wave * 16) * HDIM;

    async_copy16(gA + 0 * 1024 + se, lA + 0 * 1024);
    async_copy16(gA + 1 * 1024 + so, lA + 1 * 1024);
    async_copy16(gA + 2 * 1024 + se, lA + 2 * 1024);
    async_copy16(gA + 3 * 1024 + so, lA + 3 * 1024);
    async_copy16(gB + 0 * 1024 + se, lB + 0 * 1024);
    async_copy16(gB + 1 * 1024 + so, lB + 1 * 1024);
    async_copy16(gB + 2 * 1024 + se, lB + 2 * 1024);
    async_copy16(gB + 3 * 1024 + so, lB + 3 * 1024);

    WAIT_VM0();        // own 8 copies retired
    RAW_BARRIER();     // all waves' copies landed; LDS read-only hereafter

    // ---- fragment read bases ----
    const int key  = m15 & 7;
    const int rowA = (wm * 64 + m15) * HDIM;
    const int rowB = (wn * 64 + m15) * HDIM;
    const unsigned char* bA = tiles;
    const unsigned char* bB = tiles + TILEB;

    floatx4 acc[4][4] = {};

    // ---- barrier-free K-loop: 4 kstep-pairs x (8 ds_read_b128 + 32 MFMA)
    #pragma unroll
    for (int u = 0; u < 4; ++u) {
        const int off = ((u * 4 + g) ^ key) * 16;   // conflict-free (hdr)
        longx2 aV[4], bV[4];
        #pragma unroll
        for (int f = 0; f < 4; ++f) {
            aV[f] = *(const longx2*)(bA + rowA + f * 16 * HDIM + off);
            bV[f] = *(const longx2*)(bB + rowB + f * 16 * HDIM + off);
        }
        #pragma unroll
        for (int ks = 0; ks < 2; ++ks)
            #pragma unroll
            for (int fm = 0; fm < 4; ++fm)
                #pragma unroll
                for (int fn = 0; fn < 4; ++fn)
                    acc[fm][fn] = __builtin_amdgcn_mfma_f32_16x16x32_fp8_fp8(
                        aV[fm][ks], bV[fn][ks], acc[fm][fn], 0, 0, 0);
    }

    // ---- epilogue: e = exp2(acc) (== exp(sim/tau)), reduce rows & cols ----
    float rp[4][4] = {{0.f}};  // [fm][reg] partial row sums
    float cp[4]    = {0.f};    // [fn]      partial col sums

    if (!diag) {
        #pragma unroll
        for (int fm = 0; fm < 4; ++fm)
            #pragma unroll
            for (int fn = 0; fn < 4; ++fn) {
                const floatx4 a = acc[fm][fn];
                #pragma unroll
                for (int q = 0; q < 4; ++q) {
                    const float e = __builtin_amdgcn_exp2f(a[q]);
                    rp[fm][q] += e;
                    cp[fn]    += e;
                }
            }
    } else {
        #pragma unroll
        for (int fm = 0; fm < 4; ++fm)
            #pragma unroll
            for (int fn = 0; fn < 4; ++fn) {
                const floatx4 a = acc[fm][fn];
                const int cl = wn * 64 + fn * 16 + m15;
                #pragma unroll
                for (int q = 0; q < 4; ++q) {
                    const int rl = wm * 64 + fm * 16 + g * 4 + q;
                    float e = __builtin_amdgcn_exp2f(a[q]);
                    if (cl <= rl) e = 0.f;   // strictly-upper only
                    rp[fm][q] += e;
                    cp[fn]    += e;
                }
            }
    }

    // row sums: 16-lane DPP reduction (VALU pipe); total lands in m15==0
    #pragma unroll
    for (int fm = 0; fm < 4; ++fm)
        #pragma unroll
        for (int q = 0; q < 4; ++q) {
            float v = rp[fm][q];
            DPP_ROW_SHL_ADD(v, 0x101);   // row_shl:1
            DPP_ROW_SHL_ADD(v, 0x102);   // row_shl:2
            DPP_ROW_SHL_ADD(v, 0x104);   // row_shl:4
            DPP_ROW_SHL_ADD(v, 0x108);   // row_shl:8
            rp[fm][q] = v;
        }
    if (m15 == 0) {
        #pragma unroll
        for (int fm = 0; fm < 4; ++fm)
            #pragma unroll
            for (int q = 0; q < 4; ++q)
                atomicAdd(&rs[wm * 64 + fm * 16 + g * 4 + q], rp[fm][q]);
    }

    // col sums: reduce across quads
    #pragma unroll
    for (int mask = 16; mask < 64; mask <<= 1)
        #pragma unroll
        for (int fn = 0; fn < 4; ++fn)
            cp[fn] += __shfl_xor(cp[fn], mask);
    if (g == 0) {
        #pragma unroll
        for (int fn = 0; fn < 4; ++fn)
            atomicAdd(&cs[wn * 64 + fn * 16 + m15], cp[fn]);
    }

    __syncthreads();
    if (tid < TM) {
        atomicAdd(&rowsum[(size_t)bi * TM + tid], rs[tid]);
        atomicAdd(&rowsum[(size_t)bj * TM + tid], cs[tid]);
    }
}

// ---------------------------------------------------------------------------
// Kernel 3: loss = mean( log(rowsum_i) - 2*pos_i ), 16 blocks + atomic.
// ---------------------------------------------------------------------------
__global__ __launch_bounds__(1024) void finalize_kernel(
    const float* __restrict__ rowsum, const float* __restrict__ pos,
    float* __restrict__ out)
{
    const int i = threadIdx.x + blockIdx.x * 1024;
    float s = logf(rowsum[i]) - 2.0f * pos[i];
    #pragma unroll
    for (int off = 32; off; off >>= 1) s += __shfl_down(s, off);
    __shared__ float sh[16];
    const int lt = threadIdx.x;
    if ((lt & 63) == 0) sh[lt >> 6] = s;
    __syncthreads();
    if (lt == 0) {
        float tot = 0.f;
        #pragma unroll
        for (int w = 0; w < 16; ++w) tot += sh[w];
        atomicAdd(out, tot / (float)N2);
    }
}

// ---------------------------------------------------------------------------
extern "C" void kernel_launch(void* const* d_in, const int* in_sizes, int n_in,
                              void* d_out, int out_size, void* d_ws, size_t ws_size,
                              hipStream_t stream)
{
    const float* x = (const float*)d_in[0];
    const float* y = (const float*)d_in[1];

    // workspace: Z fp8 [16384*256] (4 MB) | rowsum f32 [16384] | pos f32 [16384]
    unsigned char* Zb = (unsigned char*)d_ws;
    float* rowsum = (float*)((char*)d_ws + (size_t)N2 * HDIM);
    float* pos    = rowsum + N2;

    normalize_kernel<<<NROWS / 4, 256, 0, stream>>>(x, y, Zb, pos, rowsum, (float*)d_out);
    simgemm_kernel<<<NBLK, 1024, 0, stream>>>(Zb, rowsum);
    finalize_kernel<<<N2 / 1024, 1024, 0, stream>>>(rowsum, pos, (float*)d_out);
}